// Round 8
// baseline (473.295 us; speedup 1.0000x reference)
//
#include <hip/hip_runtime.h>
#include <hip/hip_bf16.h>

// B,T,D = 32,4096,128. Masked last/next-observation linear interpolation.
// Proven by counters (R5): values/times = bf16, mask = 4-byte 0/1, out = fp32.
// R8 = R5's PASSING kernel + two minimal deltas:
//   (1) LDS 53KB -> 16KB via packed (nx|nt) u32 next-state  (occupancy 3->10 blk/CU)
//   (2) pass 2 re-reads v/t/m from global (L2-hot) instead of LDS stash
// Spill-free by design: no indexed register arrays, unroll kept at 8
// (R6/R7 failures attributed to scratch spills under the ctypes launcher).
#define Bq 32
#define Tq 4096
#define Dq 128
#define Lseg 32
#define NSEG (Tq / Lseg)   // 128

__device__ __forceinline__ float bfb2f(unsigned int u) {
    return __uint_as_float(u << 16);
}
__device__ __forceinline__ float ldval(const void* p, int idx, int f32) {
    if (f32) return ((const float*)p)[idx];
    return bfb2f(((const unsigned short*)p)[idx]);
}
__device__ __forceinline__ bool ldmask(const void* p, int idx, int mode) {
    switch (mode) {
        case 1:  return ((const int*)p)[idx] != 0;            // int32 0/1
        case 2:  return ((const unsigned short*)p)[idx] != 0; // bf16 0/1.0
        case 3:  return ((const unsigned int*)p)[idx] != 0;   // fp32 0/1.0
        default: return ((const unsigned char*)p)[idx] != 0;  // bool8
    }
}

__global__ __launch_bounds__(128) void interp_v8(
    const void* __restrict__ values,
    const void* __restrict__ times,
    const void* __restrict__ mask,
    float* __restrict__ out)
{
    // packed next-state: (bf16 next_x)<<16 | (bf16 next_t). 16 KB.
    // Thread-private column (only thread d touches s_n[*][d]) -> no barriers.
    __shared__ unsigned int s_n[Lseg][Dq];

    const int lane = threadIdx.x & 63;

    // ---- in-wave dtype detection (R5-verbatim, proven) ----
    int mmode, f32;
    {
        const unsigned int* mu = (const unsigned int*)mask;
        int bad_f32 = 0, bad_b16 = 0, off_nz = 0;
        for (int j = lane; j < 1024; j += 64) {       // first 4096 bytes of mask
            unsigned int w = mu[j];
            if (w != 0u && w != 0x3F800000u) bad_f32 = 1;
            unsigned int h0 = w & 0xFFFFu, h1 = w >> 16;
            if ((h0 != 0u && h0 != 0x3F80u) || (h1 != 0u && h1 != 0x3F80u)) bad_b16 = 1;
            if (w & 0xFFFFFF00u) off_nz = 1;
        }
        if      (__ballot(bad_f32) == 0ull) mmode = 3;
        else if (__ballot(bad_b16) == 0ull) mmode = 2;
        else if (__ballot(off_nz)  == 0ull) mmode = 1;
        else                                mmode = 0;

        const unsigned short* tu = (const unsigned short*)times;
        int good = 0;
        for (int k = lane; k < 256; k += 64) {
            int ex = (tu[2 * k] >> 7) & 0xFF;
            if (ex >= 118 && ex <= 142) good++;
        }
        for (int off = 32; off; off >>= 1) good += __shfl_xor(good, off, 64);
        f32 = (good < 128) ? 1 : 0;
    }

    const int g     = blockIdx.x;
    const int b     = g >> 7;            // / NSEG
    const int s     = g & (NSEG - 1);
    const int d     = threadIdx.x;       // 0..127
    const int sLo   = s * Lseg;
    const int sHi   = sLo + Lseg;
    const int ebase = b * Tq * Dq + d;

    if (f32 == 0) {
        // ========== MAIN PATH: bf16 values/times, any mask mode ==========
        // ---- backward boundary: first observation at row >= sHi (R5-style) ----
        float bx = 0.f, bt;
        {
            int found = 0, nr = 0;
            int r = sHi;
            while (r < Tq && __ballot(!found) != 0ull) {
                bool m = ldmask(mask, ebase + r * Dq, mmode);
                if (!found && m) { nr = r; found = 1; }
                ++r;
            }
            if (found) {
                bx = ldval(values, ebase + nr * Dq, 0);
                bt = ldval(times,  ebase + nr * Dq, 0);
            } else {
                bt = ldval(times, ebase + (Tq - 1) * Dq, 0);   // t_max (monotone)
            }
        }

        // ---- forward boundary: last observation at row < sLo (R5-style) ----
        float fx = 0.f, ft;
        {
            int found = 0, nr = 0;
            int r = sLo - 1;
            while (r >= 0 && __ballot(!found) != 0ull) {
                bool m = ldmask(mask, ebase + r * Dq, mmode);
                if (!found && m) { nr = r; found = 1; }
                --r;
            }
            if (found) {
                fx = ldval(values, ebase + nr * Dq, 0);
                ft = ldval(times,  ebase + nr * Dq, 0);
            } else {
                ft = ldval(times, ebase, 0);                   // times[b,0,d]
            }
        }

        // ---- pass 1: backward sweep -> packed next-state into LDS ----
        unsigned int mbits = 0;
        #pragma unroll 8
        for (int rr = Lseg - 1; rr >= 0; --rr) {
            int e = ebase + (sLo + rr) * Dq;
            float v  = ldval(values, e, 0);
            float tm = ldval(times,  e, 0);
            bool  m  = ldmask(mask,  e, mmode);
            if (m) { bx = v; bt = tm; mbits |= 1u << rr; }
            // exact: bx/bt live on the bf16 grid (loaded from bf16 buffers)
            s_n[rr][d] = (__float_as_uint(bx) & 0xFFFF0000u) | (__float_as_uint(bt) >> 16);
        }

        // ---- pass 2: forward sweep, emit fp32 (v/t/m re-read: L2-hot) ----
        #pragma unroll 8
        for (int rr = 0; rr < Lseg; ++rr) {
            int e = ebase + (sLo + rr) * Dq;
            float v  = ldval(values, e, 0);
            float tm = ldval(times,  e, 0);
            float ox;
            if (mbits & (1u << rr)) {
                fx = v; ft = tm; ox = v;
            } else {
                unsigned int pk = s_n[rr][d];
                float nx = bfb2f(pk >> 16);
                float nt = bfb2f(pk & 0xFFFFu);
                float denom = nt - ft;
                float num = fx * (nt - tm) + nx * (tm - ft);
                ox = (denom != 0.f) ? (num / denom) : 0.f;
            }
            out[e] = ox;
        }
    } else {
        // ========== FALLBACK (fp32 inputs; not expected — counters say bf16) ==
        // lazy per-element next-obs scan; correctness-only, no LDS use.
        float fx = 0.f, ft = ldval(times, ebase, 1);
        float tmax = ldval(times, ebase + (Tq - 1) * Dq, 1);
        {   // last obs before segment
            int nr = -1;
            for (int r = sLo - 1; r >= 0 && nr < 0; --r)
                if (ldmask(mask, ebase + r * Dq, mmode)) nr = r;
            if (nr >= 0) { fx = ldval(values, ebase + nr * Dq, 1); ft = ldval(times, ebase + nr * Dq, 1); }
        }
        for (int rr = 0; rr < Lseg; ++rr) {
            int r = sLo + rr;
            int e = ebase + r * Dq;
            float v  = ldval(values, e, 1);
            float tm = ldval(times,  e, 1);
            bool  m  = ldmask(mask,  e, mmode);
            float ox;
            if (m) {
                fx = v; ft = tm; ox = v;
            } else {
                float nx = 0.f, nt = tmax;
                for (int q = r + 1; q < Tq; ++q) {
                    if (ldmask(mask, ebase + q * Dq, mmode)) {
                        nx = ldval(values, ebase + q * Dq, 1);
                        nt = ldval(times,  ebase + q * Dq, 1);
                        break;
                    }
                }
                float denom = nt - ft;
                float num = fx * (nt - tm) + nx * (tm - ft);
                ox = (denom != 0.f) ? (num / denom) : 0.f;
            }
            out[e] = ox;
        }
    }
}

extern "C" void kernel_launch(void* const* d_in, const int* in_sizes, int n_in,
                              void* d_out, int out_size, void* d_ws, size_t ws_size,
                              hipStream_t stream) {
    const void* values = d_in[0];
    const void* times  = d_in[1];
    const void* mask   = d_in[2];
    float* out = (float*)d_out;
    (void)d_ws; (void)ws_size;

    interp_v8<<<Bq * NSEG, 128, 0, stream>>>(values, times, mask, out);
}